// Round 1
// baseline (61.312 us; speedup 1.0000x reference)
//
#include <hip/hip_runtime.h>
#include <hip/hip_bf16.h>

#define NFEAT 6
#define NBIN 4
#define NCLASS 10
#define NLEAF 4096
#define C2 5   // packed bf16 class pairs

__device__ __forceinline__ unsigned bf16rne(float f) {
    unsigned u = __float_as_uint(f);
    return (u + 0x7fffu + ((u >> 16) & 1u)) >> 16;   // round-nearest-even
}

__device__ __forceinline__ float sel4(float v0, float v1, float v2, float v3, int d) {
    float lo = (d & 1) ? v1 : v0;
    float hi = (d & 1) ? v3 : v2;
    return (d & 2) ? hi : lo;
}

__launch_bounds__(256, 2)
__global__ void dndt_kernel(const float* __restrict__ x,
                            const float* __restrict__ cuts,
                            const float* __restrict__ leaf_score,
                            const float* __restrict__ temperature,
                            float* __restrict__ out)
{
    __shared__ unsigned LSp[NLEAF * C2];   // 80 KB: [leaf][class-pair] bf16x2

    const int tid = threadIdx.x;

    // ---- stage leaf_score -> LDS as packed bf16 pairs ----
    for (int l = tid; l < NLEAF; l += 256) {
        const float* src = leaf_score + l * NCLASS;
        #pragma unroll
        for (int c2 = 0; c2 < C2; ++c2) {
            unsigned lo = bf16rne(src[2 * c2]);
            unsigned hi = bf16rne(src[2 * c2 + 1]);
            LSp[l * C2 + c2] = lo | (hi << 16);
        }
    }

    const int wave = (blockIdx.x << 2) + (tid >> 6);   // 0..4095
    const int lane = tid & 63;
    const float invt = 1.0f / temperature[0];

    // ---- cuts -> sorted -> bin offsets (redundant per thread, tiny) ----
    float boff[NFEAT][NBIN];
    #pragma unroll
    for (int f = 0; f < NFEAT; ++f) {
        float c0 = cuts[f * 3 + 0], c1 = cuts[f * 3 + 1], cv2 = cuts[f * 3 + 2];
        float lo01 = fminf(c0, c1), hi01 = fmaxf(c0, c1);
        float s2 = fmaxf(hi01, cv2);
        float mh = fminf(hi01, cv2);
        float s0 = fminf(lo01, mh);
        float s1 = fmaxf(lo01, mh);
        boff[f][0] = 0.0f;
        boff[f][1] = -s0;
        boff[f][2] = -s0 - s1;
        boff[f][3] = -s0 - s1 - s2;
    }

    // ---- per-row soft bins (4 rows per wave) ----
    const int row0 = wave * 4;
    float bins[4][NFEAT][NBIN];
    #pragma unroll
    for (int r = 0; r < 4; ++r) {
        const float* xr = x + (size_t)(row0 + r) * NFEAT;
        #pragma unroll
        for (int f = 0; f < NFEAT; ++f) {
            float xv = xr[f];
            float h0 = (xv * 1.0f + boff[f][0]) * invt;
            float h1 = (xv * 2.0f + boff[f][1]) * invt;
            float h2 = (xv * 3.0f + boff[f][2]) * invt;
            float h3 = (xv * 4.0f + boff[f][3]) * invt;
            float m = fmaxf(fmaxf(h0, h1), fmaxf(h2, h3));
            float e0 = __expf(h0 - m), e1 = __expf(h1 - m);
            float e2 = __expf(h2 - m), e3 = __expf(h3 - m);
            float rs = 1.0f / (e0 + e1 + e2 + e3);
            bins[r][f][0] = e0 * rs;
            bins[r][f][1] = e1 * rs;
            bins[r][f][2] = e2 * rs;
            bins[r][f][3] = e3 * rs;
        }
    }

    // ---- lane-local leafB over features 3..5 (lane = bb = l3*16+l4*4+l5) ----
    const int l3 = lane >> 4, l4 = (lane >> 2) & 3, l5 = lane & 3;
    float pb[4];
    #pragma unroll
    for (int r = 0; r < 4; ++r) {
        float b3 = sel4(bins[r][3][0], bins[r][3][1], bins[r][3][2], bins[r][3][3], l3);
        float b4 = sel4(bins[r][4][0], bins[r][4][1], bins[r][4][2], bins[r][4][3], l4);
        float b5 = sel4(bins[r][5][0], bins[r][5][1], bins[r][5][2], bins[r][5][3], l5);
        pb[r] = b3 * b4 * b5;
    }

    float acc[4][NCLASS];
    #pragma unroll
    for (int r = 0; r < 4; ++r)
        #pragma unroll
        for (int c = 0; c < NCLASS; ++c) acc[r][c] = 0.0f;

    __syncthreads();

    // ---- main contraction: loop over a = (l0,l1,l2), lane = bb ----
    #pragma unroll 1
    for (int l0 = 0; l0 < 4; ++l0) {
        float p0[4];
        #pragma unroll
        for (int r = 0; r < 4; ++r)
            p0[r] = sel4(bins[r][0][0], bins[r][0][1], bins[r][0][2], bins[r][0][3], l0);
        const unsigned* base = LSp + ((size_t)l0 * 1024 + lane) * C2;
        #pragma unroll
        for (int l1 = 0; l1 < 4; ++l1) {
            float p01[4];
            #pragma unroll
            for (int r = 0; r < 4; ++r) p01[r] = p0[r] * bins[r][1][l1];
            #pragma unroll
            for (int l2 = 0; l2 < 4; ++l2) {
                float pa[4];
                #pragma unroll
                for (int r = 0; r < 4; ++r) pa[r] = p01[r] * bins[r][2][l2];
                const unsigned* p = base + (l1 * 4 + l2) * 64 * C2;
                #pragma unroll
                for (int c2 = 0; c2 < C2; ++c2) {
                    unsigned w = p[c2];
                    float flo = __uint_as_float(w << 16);
                    float fhi = __uint_as_float(w & 0xffff0000u);
                    #pragma unroll
                    for (int r = 0; r < 4; ++r) {
                        acc[r][2 * c2]     = fmaf(pa[r], flo, acc[r][2 * c2]);
                        acc[r][2 * c2 + 1] = fmaf(pa[r], fhi, acc[r][2 * c2 + 1]);
                    }
                }
            }
        }
    }

    // ---- scale by leafB, wave-reduce, write ----
    #pragma unroll
    for (int r = 0; r < 4; ++r) {
        #pragma unroll
        for (int c = 0; c < NCLASS; ++c) {
            float s = acc[r][c] * pb[r];
            s += __shfl_xor(s, 1, 64);
            s += __shfl_xor(s, 2, 64);
            s += __shfl_xor(s, 4, 64);
            s += __shfl_xor(s, 8, 64);
            s += __shfl_xor(s, 16, 64);
            s += __shfl_xor(s, 32, 64);
            if (lane == 0) out[(size_t)(row0 + r) * NCLASS + c] = s;
        }
    }
}

extern "C" void kernel_launch(void* const* d_in, const int* in_sizes, int n_in,
                              void* d_out, int out_size, void* d_ws, size_t ws_size,
                              hipStream_t stream) {
    const float* x           = (const float*)d_in[0];
    const float* cuts        = (const float*)d_in[1];
    const float* leaf_score  = (const float*)d_in[2];
    const float* temperature = (const float*)d_in[3];
    float* out = (float*)d_out;
    // 16384 rows / 4 rows-per-wave = 4096 waves; 4 waves per 256-thread block
    dndt_kernel<<<1024, 256, 0, stream>>>(x, cuts, leaf_score, temperature, out);
}

// Round 2
// 57.561 us; speedup vs baseline: 1.0652x; 1.0652x over previous
//
#include <hip/hip_runtime.h>
#include <hip/hip_bf16.h>

#define NFEAT 6
#define NBIN 4
#define NCLASS 10
#define NLEAF 4096
#define C2 5                 // packed bf16 class pairs per leaf
#define NWORDS (NLEAF * C2)  // 20480 packed words = 80 KB

__device__ __forceinline__ unsigned bf16rne(float f) {
    unsigned u = __float_as_uint(f);
    return (u + 0x7fffu + ((u >> 16) & 1u)) >> 16;   // round-nearest-even
}

__device__ __forceinline__ float sel4(float v0, float v1, float v2, float v3, int d) {
    float lo = (d & 1) ? v1 : v0;
    float hi = (d & 1) ? v3 : v2;
    return (d & 2) ? hi : lo;
}

// ---- prepass: leaf_score f32 -> packed bf16x2 words in workspace ----
__launch_bounds__(256)
__global__ void pack_kernel(const float* __restrict__ ls, unsigned* __restrict__ ws) {
    int t = blockIdx.x * 256 + threadIdx.x;          // 0..10239, one float4 each
    float4 v = ((const float4*)ls)[t];
    ws[2 * t]     = bf16rne(v.x) | (bf16rne(v.y) << 16);
    ws[2 * t + 1] = bf16rne(v.z) | (bf16rne(v.w) << 16);
}

template<bool WS>
__launch_bounds__(512, 4)
__global__ void dndt_kernel(const float* __restrict__ x,
                            const float* __restrict__ cuts,
                            const float* __restrict__ lsf,
                            const unsigned* __restrict__ lsw,
                            const float* __restrict__ temperature,
                            float* __restrict__ out)
{
    __shared__ unsigned LSp[NWORDS];   // 80 KB: flat [leaf*5 + c2] bf16x2

    const int tid = threadIdx.x;

    // ---- stage packed leaf_score -> LDS ----
    if (WS) {
        const uint4* src = (const uint4*)lsw;        // 5120 uint4
        #pragma unroll
        for (int i = 0; i < 10; ++i) {
            int t = i * 512 + tid;
            *(uint4*)&LSp[4 * t] = src[t];
        }
    } else {
        const float4* src = (const float4*)lsf;      // 10240 float4
        #pragma unroll
        for (int i = 0; i < 20; ++i) {
            int t = i * 512 + tid;
            float4 v = src[t];
            LSp[2 * t]     = bf16rne(v.x) | (bf16rne(v.y) << 16);
            LSp[2 * t + 1] = bf16rne(v.z) | (bf16rne(v.w) << 16);
        }
    }

    const int wave = (blockIdx.x << 3) + (tid >> 6);   // 0..4095
    const int lane = tid & 63;
    // fold 1/t and log2(e) into the logits so exp2f -> bare v_exp_f32
    const float s = 1.44269504088896f / temperature[0];

    // ---- cuts -> sorted -> scaled bin offsets (uniform, tiny) ----
    float boff[NFEAT][NBIN];
    #pragma unroll
    for (int f = 0; f < NFEAT; ++f) {
        float c0 = cuts[f * 3 + 0], c1 = cuts[f * 3 + 1], cv2 = cuts[f * 3 + 2];
        float lo01 = fminf(c0, c1), hi01 = fmaxf(c0, c1);
        float s2 = fmaxf(hi01, cv2);
        float mh = fminf(hi01, cv2);
        float s0 = fminf(lo01, mh);
        float s1 = fmaxf(lo01, mh);
        boff[f][0] = 0.0f;
        boff[f][1] = -s0 * s;
        boff[f][2] = (-s0 - s1) * s;
        boff[f][3] = (-s0 - s1 - s2) * s;
    }
    const float w1 = 1.0f * s, w2 = 2.0f * s, w3 = 3.0f * s, w4 = 4.0f * s;

    // ---- per-row soft bins (4 rows per wave) ----
    const int row0 = wave * 4;
    float bins[4][NFEAT][NBIN];
    #pragma unroll
    for (int r = 0; r < 4; ++r) {
        const float* xr = x + (size_t)(row0 + r) * NFEAT;
        #pragma unroll
        for (int f = 0; f < NFEAT; ++f) {
            float xv = xr[f];
            float h0 = fmaf(xv, w1, boff[f][0]);
            float h1 = fmaf(xv, w2, boff[f][1]);
            float h2 = fmaf(xv, w3, boff[f][2]);
            float h3 = fmaf(xv, w4, boff[f][3]);
            float m = fmaxf(fmaxf(h0, h1), fmaxf(h2, h3));
            float e0 = exp2f(h0 - m), e1 = exp2f(h1 - m);
            float e2 = exp2f(h2 - m), e3 = exp2f(h3 - m);
            float rs = 1.0f / (e0 + e1 + e2 + e3);
            bins[r][f][0] = e0 * rs;
            bins[r][f][1] = e1 * rs;
            bins[r][f][2] = e2 * rs;
            bins[r][f][3] = e3 * rs;
        }
    }

    // ---- lane-local leafB over features 3..5 (lane = l3*16+l4*4+l5) ----
    const int l3 = lane >> 4, l4 = (lane >> 2) & 3, l5 = lane & 3;
    float pb[4];
    #pragma unroll
    for (int r = 0; r < 4; ++r) {
        float b3 = sel4(bins[r][3][0], bins[r][3][1], bins[r][3][2], bins[r][3][3], l3);
        float b4 = sel4(bins[r][4][0], bins[r][4][1], bins[r][4][2], bins[r][4][3], l4);
        float b5 = sel4(bins[r][5][0], bins[r][5][1], bins[r][5][2], bins[r][5][3], l5);
        pb[r] = b3 * b4 * b5;
    }

    float acc[4][NCLASS];
    #pragma unroll
    for (int r = 0; r < 4; ++r)
        #pragma unroll
        for (int c = 0; c < NCLASS; ++c) acc[r][c] = 0.0f;

    __syncthreads();

    // ---- main contraction: loop over a = (l0,l1,l2), lane = bb ----
    #pragma unroll 1
    for (int l0 = 0; l0 < 4; ++l0) {
        float p0[4];
        #pragma unroll
        for (int r = 0; r < 4; ++r)
            p0[r] = sel4(bins[r][0][0], bins[r][0][1], bins[r][0][2], bins[r][0][3], l0);
        const unsigned* base = LSp + ((size_t)l0 * 1024 + lane) * C2;
        #pragma unroll
        for (int l1 = 0; l1 < 4; ++l1) {
            float p01[4];
            #pragma unroll
            for (int r = 0; r < 4; ++r) p01[r] = p0[r] * bins[r][1][l1];
            #pragma unroll
            for (int l2 = 0; l2 < 4; ++l2) {
                float pa[4];
                #pragma unroll
                for (int r = 0; r < 4; ++r) pa[r] = p01[r] * bins[r][2][l2];
                const unsigned* p = base + (l1 * 4 + l2) * 64 * C2;
                #pragma unroll
                for (int c2 = 0; c2 < C2; ++c2) {
                    unsigned w = p[c2];
                    float flo = __uint_as_float(w << 16);
                    float fhi = __uint_as_float(w & 0xffff0000u);
                    #pragma unroll
                    for (int r = 0; r < 4; ++r) {
                        acc[r][2 * c2]     = fmaf(pa[r], flo, acc[r][2 * c2]);
                        acc[r][2 * c2 + 1] = fmaf(pa[r], fhi, acc[r][2 * c2 + 1]);
                    }
                }
            }
        }
    }

    // ---- scale by leafB, wave-reduce, write ----
    #pragma unroll
    for (int r = 0; r < 4; ++r) {
        #pragma unroll
        for (int c = 0; c < NCLASS; ++c) {
            float v = acc[r][c] * pb[r];
            v += __shfl_xor(v, 1, 64);
            v += __shfl_xor(v, 2, 64);
            v += __shfl_xor(v, 4, 64);
            v += __shfl_xor(v, 8, 64);
            v += __shfl_xor(v, 16, 64);
            v += __shfl_xor(v, 32, 64);
            if (lane == 0) out[(size_t)(row0 + r) * NCLASS + c] = v;
        }
    }
}

extern "C" void kernel_launch(void* const* d_in, const int* in_sizes, int n_in,
                              void* d_out, int out_size, void* d_ws, size_t ws_size,
                              hipStream_t stream) {
    const float* x           = (const float*)d_in[0];
    const float* cuts        = (const float*)d_in[1];
    const float* leaf_score  = (const float*)d_in[2];
    const float* temperature = (const float*)d_in[3];
    float* out = (float*)d_out;

    if (ws_size >= NWORDS * sizeof(unsigned)) {
        unsigned* ws = (unsigned*)d_ws;
        pack_kernel<<<40, 256, 0, stream>>>(leaf_score, ws);
        // 16384 rows / 4 per wave = 4096 waves; 8 waves per 512-thread block
        dndt_kernel<true><<<512, 512, 0, stream>>>(x, cuts, leaf_score, ws,
                                                   temperature, out);
    } else {
        dndt_kernel<false><<<512, 512, 0, stream>>>(x, cuts, leaf_score, nullptr,
                                                    temperature, out);
    }
}

// Round 3
// 21.024 us; speedup vs baseline: 2.9163x; 2.7379x over previous
//
#include <hip/hip_runtime.h>
#include <hip/hip_bf16.h>

#define NCLASS 10
#define WS_BYTES 81920   // [10][4096] bf16, swizzled

typedef __bf16 bf16x8 __attribute__((ext_vector_type(8)));
typedef float  f32x4  __attribute__((ext_vector_type(4)));

__device__ __forceinline__ unsigned short bf16rne_u16(float f) {
    unsigned u = __float_as_uint(f);
    return (unsigned short)((u + 0x7fffu + ((u >> 16) & 1u)) >> 16);
}
__device__ __forceinline__ float sel4(float v0, float v1, float v2, float v3, int d) {
    float lo = (d & 1) ? v1 : v0;
    float hi = (d & 1) ? v3 : v2;
    return (d & 2) ? hi : lo;
}

// ---- prepass: leaf_score [4096][10] f32 -> ws [10][4096] bf16, XOR-swizzled ----
// element (n,k) lives at byte  n*8192 + ((2k) ^ ((n&7)<<4))
__launch_bounds__(256)
__global__ void pack_t_kernel(const float* __restrict__ ls, char* __restrict__ ws) {
    int k = blockIdx.x * 256 + threadIdx.x;      // 0..4095
    #pragma unroll
    for (int n = 0; n < NCLASS; ++n) {
        unsigned short b = bf16rne_u16(ls[k * NCLASS + n]);
        unsigned addr = ((unsigned)n << 13) + (((unsigned)(k << 1)) ^ (((unsigned)(n & 7)) << 4));
        *(unsigned short*)(ws + addr) = b;
    }
}

template<bool WS>
__launch_bounds__(512, 4)
__global__ void dndt_mfma(const float* __restrict__ x,
                          const float* __restrict__ cuts,
                          const float* __restrict__ lsf,
                          const char* __restrict__ wsb,
                          const float* __restrict__ temperature,
                          float* __restrict__ out)
{
    __shared__ char LS[WS_BYTES];   // B-matrix bf16 [10][4096] swizzled; later reused as reduce scratch
    const int tid = threadIdx.x;

    // ---- stage B into LDS ----
    if (WS) {
        const uint4* src = (const uint4*)wsb;
        uint4* dst = (uint4*)LS;
        #pragma unroll
        for (int i = 0; i < 10; ++i) dst[i * 512 + tid] = src[i * 512 + tid];
    } else {
        #pragma unroll
        for (int i = 0; i < 8; ++i) {
            int k = i * 512 + tid;
            #pragma unroll
            for (int n = 0; n < NCLASS; ++n) {
                unsigned short b = bf16rne_u16(lsf[k * NCLASS + n]);
                unsigned addr = ((unsigned)n << 13) + (((unsigned)(k << 1)) ^ (((unsigned)(n & 7)) << 4));
                *(unsigned short*)(LS + addr) = b;
            }
        }
    }

    const int wave = tid >> 6, lane = tid & 63;
    const int rt = wave >> 2;        // row-tile within block (0..1)
    const int ks = wave & 3;         // K-split (each wave: 32 MFMAs, l0 = ks)
    const int r  = lane & 15;        // A-row within tile AND B/D column (class)
    const int kg = lane >> 4;        // k-group (8 k's per lane per MFMA)
    const int row = (blockIdx.x << 5) + (rt << 4) + r;   // global batch row

    const float sc = 1.44269504088896f / temperature[0]; // log2(e)/t folded in

    // ---- soft bins for this lane's row (exp2-form softmax over 4 logits × 6 feats) ----
    float bins[6][4];
    {
        const float2* x2 = (const float2*)x;
        float2 p0 = x2[row * 3 + 0], p1 = x2[row * 3 + 1], p2 = x2[row * 3 + 2];
        float xv[6] = {p0.x, p0.y, p1.x, p1.y, p2.x, p2.y};
        #pragma unroll
        for (int f = 0; f < 6; ++f) {
            float c0 = cuts[f * 3 + 0], c1 = cuts[f * 3 + 1], cv = cuts[f * 3 + 2];
            float lo01 = fminf(c0, c1), hi01 = fmaxf(c0, c1);
            float s2 = fmaxf(hi01, cv), mh = fminf(hi01, cv);
            float s0 = fminf(lo01, mh), s1 = fmaxf(lo01, mh);
            float h0 = xv[f] * sc;
            float h1 = fmaf(xv[f], 2.f * sc, -s0 * sc);
            float h2 = fmaf(xv[f], 3.f * sc, (-s0 - s1) * sc);
            float h3 = fmaf(xv[f], 4.f * sc, (-s0 - s1 - s2) * sc);
            float m = fmaxf(fmaxf(h0, h1), fmaxf(h2, h3));
            float e0 = exp2f(h0 - m), e1 = exp2f(h1 - m);
            float e2 = exp2f(h2 - m), e3 = exp2f(h3 - m);
            float rs = 1.f / (e0 + e1 + e2 + e3);
            bins[f][0] = e0 * rs; bins[f][1] = e1 * rs;
            bins[f][2] = e2 * rs; bins[f][3] = e3 * rs;
        }
    }

    // ---- per-lane constants: k = (mstep<<5)|(kg<<3)|j, digits l5=j&3, l4=2(kg&1)+(j>>2),
    //      l3=2(m&1)+(kg>>1), l2=(m>>1)&3, l1=(m>>3)&3, l0=ks ----
    const int kgl = kg & 1, kgh = kg >> 1;
    float t8[8];
    #pragma unroll
    for (int j = 0; j < 8; ++j) {
        float b4 = kgl ? bins[4][2 + (j >> 2)] : bins[4][(j >> 2)];
        t8[j] = b4 * bins[5][j & 3];
    }
    const float b3e = kgh ? bins[3][1] : bins[3][0];
    const float b3o = kgh ? bins[3][3] : bins[3][2];
    const float b0  = sel4(bins[0][0], bins[0][1], bins[0][2], bins[0][3], ks);

    // ---- B-read base addresses (swizzle bits 4-5 in base, bit 6 via even/odd bases) ----
    const int n_eff = (r < NCLASS) ? r : 9;               // cols >=10 are don't-care (broadcast row 9)
    const unsigned base0 = ((unsigned)n_eff << 13) +
                           ((((unsigned)kg) << 4) ^ ((((unsigned)n_eff) & 3u) << 4));
    const unsigned c6 = (((unsigned)n_eff) >> 2) & 1u;
    const int be = (int)(base0 + (c6 << 6)) + ks * 2048;        // even msteps
    const int bo = (int)(base0 + ((1u - c6) << 6)) + ks * 2048; // odd msteps

    __syncthreads();

    // ---- K-loop: 32 MFMAs, A generated in-register ----
    f32x4 acc = {0.f, 0.f, 0.f, 0.f};
    #pragma unroll
    for (int m1 = 0; m1 < 4; ++m1) {
        const float b01 = b0 * bins[1][m1];
        #pragma unroll
        for (int m2 = 0; m2 < 4; ++m2) {
            const float b012 = b01 * bins[2][m2];
            const int off = (m1 * 4 + m2) * 128;
            {   // even mstep: l3 = kg>>1
                float base = b012 * b3e;
                bf16x8 a;
                #pragma unroll
                for (int j = 0; j < 8; ++j) a[j] = (__bf16)(base * t8[j]);
                bf16x8 b = *(const bf16x8*)(LS + (be + off));
                acc = __builtin_amdgcn_mfma_f32_16x16x32_bf16(a, b, acc, 0, 0, 0);
            }
            {   // odd mstep: l3 = 2 + (kg>>1)
                float base = b012 * b3o;
                bf16x8 a;
                #pragma unroll
                for (int j = 0; j < 8; ++j) a[j] = (__bf16)(base * t8[j]);
                bf16x8 b = *(const bf16x8*)(LS + (bo + off));
                acc = __builtin_amdgcn_mfma_f32_16x16x32_bf16(a, b, acc, 0, 0, 0);
            }
        }
    }

    // ---- reduce the 4 K-split partials through LDS (reuse staging buffer) ----
    __syncthreads();
    float* red = (float*)LS;
    *(f32x4*)&red[((size_t)wave * 64 + lane) * 4] = acc;
    __syncthreads();
    if (ks == 0) {
        f32x4 p1 = *(f32x4*)&red[(((size_t)rt * 4 + 1) * 64 + lane) * 4];
        f32x4 p2 = *(f32x4*)&red[(((size_t)rt * 4 + 2) * 64 + lane) * 4];
        f32x4 p3 = *(f32x4*)&red[(((size_t)rt * 4 + 3) * 64 + lane) * 4];
        f32x4 tot = acc + p1 + p2 + p3;
        if (r < NCLASS) {   // D: col = lane&15 = class, row = kg*4 + q
            #pragma unroll
            for (int q = 0; q < 4; ++q) {
                int grow = (blockIdx.x << 5) + (rt << 4) + kg * 4 + q;
                out[(size_t)grow * NCLASS + r] = tot[q];
            }
        }
    }
}

extern "C" void kernel_launch(void* const* d_in, const int* in_sizes, int n_in,
                              void* d_out, int out_size, void* d_ws, size_t ws_size,
                              hipStream_t stream) {
    const float* x           = (const float*)d_in[0];
    const float* cuts        = (const float*)d_in[1];
    const float* leaf_score  = (const float*)d_in[2];
    const float* temperature = (const float*)d_in[3];
    float* out = (float*)d_out;

    if (ws_size >= WS_BYTES) {
        char* ws = (char*)d_ws;
        pack_t_kernel<<<16, 256, 0, stream>>>(leaf_score, ws);
        dndt_mfma<true><<<512, 512, 0, stream>>>(x, cuts, leaf_score, ws, temperature, out);
    } else {
        dndt_mfma<false><<<512, 512, 0, stream>>>(x, cuts, leaf_score, nullptr, temperature, out);
    }
}

// Round 4
// 16.685 us; speedup vs baseline: 3.6747x; 1.2600x over previous
//
#include <hip/hip_runtime.h>
#include <hip/hip_bf16.h>

#define NCLASS 10
#define WS_BYTES 81920                 // B: [10][4096] bf16, XOR-swizzled
#define BINS_OFF 81920                 // bins region after B
#define BINS_STRIDE 28                 // dwords per row (24 used, padded vs banks)
#define LDS_BYTES (WS_BYTES + 64 * BINS_STRIDE * 4)   // 89088 B -> 1 block/CU, 16 waves

typedef __bf16 bf16x8 __attribute__((ext_vector_type(8)));
typedef float  f32x4  __attribute__((ext_vector_type(4)));
typedef float  f32x2  __attribute__((ext_vector_type(2)));

__device__ __forceinline__ unsigned short bf16rne_u16(float f) {
    unsigned u = __float_as_uint(f);
    return (unsigned short)((u + 0x7fffu + ((u >> 16) & 1u)) >> 16);
}

// ---- prepass: leaf_score [4096][10] f32 -> ws [10][4096] bf16, XOR-swizzled ----
// element (n,k) lives at byte  n*8192 + ((2k) ^ ((n&7)<<4))
__launch_bounds__(256)
__global__ void pack_t_kernel(const float* __restrict__ ls, char* __restrict__ ws) {
    int k = blockIdx.x * 256 + threadIdx.x;      // 0..4095
    #pragma unroll
    for (int n = 0; n < NCLASS; ++n) {
        unsigned short b = bf16rne_u16(ls[k * NCLASS + n]);
        unsigned addr = ((unsigned)n << 13) + (((unsigned)(k << 1)) ^ (((unsigned)(n & 7)) << 4));
        *(unsigned short*)(ws + addr) = b;
    }
}

__device__ __forceinline__ bf16x8 mk_a(const f32x2* t8v, float base) {
    bf16x8 a;
    #pragma unroll
    for (int i = 0; i < 4; ++i) {
        f32x2 p = t8v[i] * base;       // v_pk_mul_f32
        a[2 * i]     = (__bf16)p[0];   // pairs -> v_cvt_pk_bf16_f32
        a[2 * i + 1] = (__bf16)p[1];
    }
    return a;
}

template<bool WS>
__launch_bounds__(1024, 4)
__global__ void dndt_mfma(const float* __restrict__ x,
                          const float* __restrict__ cuts,
                          const float* __restrict__ lsf,
                          const char* __restrict__ wsb,
                          const float* __restrict__ temperature,
                          float* __restrict__ out)
{
    __shared__ char LS[LDS_BYTES];
    const int tid = threadIdx.x;

    // ---- stage B into LDS (1024 threads, 5 uint4 each) ----
    if (WS) {
        const uint4* src = (const uint4*)wsb;    // 5120 uint4
        uint4* dst = (uint4*)LS;
        #pragma unroll
        for (int i = 0; i < 5; ++i) dst[i * 1024 + tid] = src[i * 1024 + tid];
    } else {
        #pragma unroll
        for (int i = 0; i < 4; ++i) {
            int k = i * 1024 + tid;
            #pragma unroll
            for (int n = 0; n < NCLASS; ++n) {
                unsigned short b = bf16rne_u16(lsf[k * NCLASS + n]);
                unsigned addr = ((unsigned)n << 13) + (((unsigned)(k << 1)) ^ (((unsigned)(n & 7)) << 4));
                *(unsigned short*)(LS + addr) = b;
            }
        }
    }

    // ---- block-shared soft bins: 64 rows x 6 feats, one softmax per thread ----
    float* BINS = (float*)(LS + BINS_OFF);       // [64][BINS_STRIDE] f32
    const float sc = 1.44269504088896f / temperature[0];   // log2(e)/t
    if (tid < 512) {
        const int rl = tid >> 3, f = tid & 7;
        if (f < 6) {
            const int grow = (blockIdx.x << 6) + rl;
            float xv = x[grow * 6 + f];
            float c0 = cuts[f * 3 + 0], c1 = cuts[f * 3 + 1], cv = cuts[f * 3 + 2];
            float lo01 = fminf(c0, c1), hi01 = fmaxf(c0, c1);
            float s2 = fmaxf(hi01, cv), mh = fminf(hi01, cv);
            float s0 = fminf(lo01, mh), s1 = fmaxf(lo01, mh);
            float h0 = xv * sc;
            float h1 = fmaf(xv, 2.f * sc, -s0 * sc);
            float h2 = fmaf(xv, 3.f * sc, (-s0 - s1) * sc);
            float h3 = fmaf(xv, 4.f * sc, (-s0 - s1 - s2) * sc);
            float m = fmaxf(fmaxf(h0, h1), fmaxf(h2, h3));
            float e0 = exp2f(h0 - m), e1 = exp2f(h1 - m);
            float e2 = exp2f(h2 - m), e3 = exp2f(h3 - m);
            float rs = 1.f / (e0 + e1 + e2 + e3);
            f32x4 b = {e0 * rs, e1 * rs, e2 * rs, e3 * rs};
            *(f32x4*)&BINS[rl * BINS_STRIDE + f * 4] = b;
        }
    }

    __syncthreads();

    // ---- per-thread geometry ----
    const int wave = tid >> 6, lane = tid & 63;
    const int rt = wave >> 2;            // row-tile (0..3)
    const int ks = wave & 3;             // K-split: l0 = ks
    const int r  = lane & 15;            // A-row within tile AND B/D column
    const int kg = lane >> 4;            // k-group
    const int rl = rt * 16 + r;          // local row

    const float* BR = &BINS[rl * BINS_STRIDE];
    f32x4 b0v = *(const f32x4*)&BR[0];
    f32x4 b1v = *(const f32x4*)&BR[4];
    f32x4 b2v = *(const f32x4*)&BR[8];
    f32x4 b3v = *(const f32x4*)&BR[12];
    f32x4 b4v = *(const f32x4*)&BR[16];
    f32x4 b5v = *(const f32x4*)&BR[20];

    // t8[j] = bins4[2*(kg&1)+(j>>2)] * bins5[j&3], as f32x2 pairs
    const int kgl = kg & 1, kgh = kg >> 1;
    f32x2 t8v[4];
    {
        float b4a = b4v[kgl * 2 + 0], b4b = b4v[kgl * 2 + 1];
        t8v[0] = (f32x2){b4a * b5v[0], b4a * b5v[1]};
        t8v[1] = (f32x2){b4a * b5v[2], b4a * b5v[3]};
        t8v[2] = (f32x2){b4b * b5v[0], b4b * b5v[1]};
        t8v[3] = (f32x2){b4b * b5v[2], b4b * b5v[3]};
    }
    const float b3e = b3v[kgh];          // even mstep: l3 = kg>>1
    const float b3o = b3v[2 + kgh];      // odd  mstep: l3 = 2 + (kg>>1)
    const float b0  = b0v[ks];

    // ---- B-read base addresses (swizzle bits 4-5 in base, bit 6 via even/odd) ----
    const int n_eff = (r < NCLASS) ? r : 9;
    const unsigned base0 = ((unsigned)n_eff << 13) +
                           ((((unsigned)kg) << 4) ^ ((((unsigned)n_eff) & 3u) << 4));
    const unsigned c6 = (((unsigned)n_eff) >> 2) & 1u;
    const int be = (int)(base0 + (c6 << 6)) + ks * 2048;
    const int bo = (int)(base0 + ((1u - c6) << 6)) + ks * 2048;

    // ---- K-loop: 32 MFMAs, A generated in-register ----
    f32x4 acc = {0.f, 0.f, 0.f, 0.f};
    #pragma unroll
    for (int m1 = 0; m1 < 4; ++m1) {
        const float b01 = b0 * b1v[m1];
        #pragma unroll
        for (int m2 = 0; m2 < 4; ++m2) {
            const float b012 = b01 * b2v[m2];
            const int off = (m1 * 4 + m2) * 128;
            {
                bf16x8 a = mk_a(t8v, b012 * b3e);
                bf16x8 b = *(const bf16x8*)(LS + (be + off));
                acc = __builtin_amdgcn_mfma_f32_16x16x32_bf16(a, b, acc, 0, 0, 0);
            }
            {
                bf16x8 a = mk_a(t8v, b012 * b3o);
                bf16x8 b = *(const bf16x8*)(LS + (bo + off));
                acc = __builtin_amdgcn_mfma_f32_16x16x32_bf16(a, b, acc, 0, 0, 0);
            }
        }
    }

    // ---- reduce K-split partials through LDS (reuse B region) ----
    __syncthreads();
    float* red = (float*)LS;
    *(f32x4*)&red[((size_t)wave * 64 + lane) * 4] = acc;
    __syncthreads();
    if (ks == 0) {
        f32x4 p1 = *(f32x4*)&red[(((size_t)rt * 4 + 1) * 64 + lane) * 4];
        f32x4 p2 = *(f32x4*)&red[(((size_t)rt * 4 + 2) * 64 + lane) * 4];
        f32x4 p3 = *(f32x4*)&red[(((size_t)rt * 4 + 3) * 64 + lane) * 4];
        f32x4 tot = acc + p1 + p2 + p3;
        if (r < NCLASS) {   // D: col = lane&15 = class, row = kg*4 + q
            #pragma unroll
            for (int q = 0; q < 4; ++q) {
                int grow = (blockIdx.x << 6) + (rt << 4) + kg * 4 + q;
                out[(size_t)grow * NCLASS + r] = tot[q];
            }
        }
    }
}

extern "C" void kernel_launch(void* const* d_in, const int* in_sizes, int n_in,
                              void* d_out, int out_size, void* d_ws, size_t ws_size,
                              hipStream_t stream) {
    const float* x           = (const float*)d_in[0];
    const float* cuts        = (const float*)d_in[1];
    const float* leaf_score  = (const float*)d_in[2];
    const float* temperature = (const float*)d_in[3];
    float* out = (float*)d_out;

    if (ws_size >= WS_BYTES) {
        char* ws = (char*)d_ws;
        pack_t_kernel<<<16, 256, 0, stream>>>(leaf_score, ws);
        // 16384 rows / 64 rows-per-block = 256 blocks (1 per CU), 16 waves each
        dndt_mfma<true><<<256, 1024, 0, stream>>>(x, cuts, leaf_score, ws, temperature, out);
    } else {
        dndt_mfma<false><<<256, 1024, 0, stream>>>(x, cuts, leaf_score, nullptr, temperature, out);
    }
}

// Round 5
// 12.062 us; speedup vs baseline: 5.0830x; 1.3832x over previous
//
#include <hip/hip_runtime.h>
#include <hip/hip_bf16.h>

#define NCLASS 10
#define B_BYTES 81920                  // B: [10][4096] bf16, XOR-swizzled
#define BINS_OFF 81920                 // bins region after B
#define BINS_STRIDE 28                 // dwords per row (24 used, padded vs banks)
#define LDS_BYTES (B_BYTES + 64 * BINS_STRIDE * 4)   // 89088 B -> 1 block/CU, 16 waves

typedef __bf16 bf16x8 __attribute__((ext_vector_type(8)));
typedef __bf16 bf16x2 __attribute__((ext_vector_type(2)));
typedef float  f32x4  __attribute__((ext_vector_type(4)));
typedef float  f32x2  __attribute__((ext_vector_type(2)));

__device__ __forceinline__ unsigned pack2(float lo, float hi) {
    bf16x2 p = {(__bf16)lo, (__bf16)hi};        // v_cvt_pk_bf16_f32
    return __builtin_bit_cast(unsigned, p);
}

__device__ __forceinline__ bf16x8 mk_a(const f32x2* t8v, float base) {
    bf16x8 a;
    #pragma unroll
    for (int i = 0; i < 4; ++i) {
        f32x2 p = t8v[i] * base;                // v_pk_mul_f32
        a[2 * i]     = (__bf16)p[0];            // pairs -> v_cvt_pk_bf16_f32
        a[2 * i + 1] = (__bf16)p[1];
    }
    return a;
}

__launch_bounds__(1024, 4)
__global__ void dndt_mfma(const float* __restrict__ x,
                          const float* __restrict__ cuts,
                          const float* __restrict__ ls,
                          const float* __restrict__ temperature,
                          float* __restrict__ out)
{
    __shared__ __attribute__((aligned(16))) char LS[LDS_BYTES];
    const int tid = threadIdx.x;

    // ---- in-kernel pack: leaf_score [4096][10] f32 -> LDS [10][4096] bf16 swizzled ----
    // element (n,k) at byte n*8192 + ((2k) ^ ((n&7)<<4)); pair (2j,2j+1) shares a dword.
    {
        const float4* ls4 = (const float4*)ls;   // 10240 float4
        #pragma unroll
        for (int pp = 0; pp < 2; ++pp) {
            const int j = pp * 1024 + tid;       // leaf pair 0..2047
            float4 f0 = ls4[5 * j + 0];
            float4 f1 = ls4[5 * j + 1];
            float4 f2 = ls4[5 * j + 2];
            float4 f3 = ls4[5 * j + 3];
            float4 f4 = ls4[5 * j + 4];
            float k0[10] = {f0.x, f0.y, f0.z, f0.w, f1.x, f1.y, f1.z, f1.w, f2.x, f2.y};
            float k1[10] = {f2.z, f2.w, f3.x, f3.y, f3.z, f3.w, f4.x, f4.y, f4.z, f4.w};
            #pragma unroll
            for (int n = 0; n < NCLASS; ++n) {
                unsigned addr = ((unsigned)n << 13) +
                                (((unsigned)(j << 2)) ^ (((unsigned)(n & 7)) << 4));
                *(unsigned*)(LS + addr) = pack2(k0[n], k1[n]);
            }
        }
    }

    // ---- block-shared soft bins: 64 rows x 6 feats, one softmax per thread ----
    float* BINS = (float*)(LS + BINS_OFF);       // [64][BINS_STRIDE] f32
    const float sc = 1.44269504088896f / temperature[0];   // log2(e)/t
    if (tid < 512) {
        const int rl = tid >> 3, f = tid & 7;
        if (f < 6) {
            const int grow = (blockIdx.x << 6) + rl;
            float xv = x[grow * 6 + f];
            float c0 = cuts[f * 3 + 0], c1 = cuts[f * 3 + 1], cv = cuts[f * 3 + 2];
            float lo01 = fminf(c0, c1), hi01 = fmaxf(c0, c1);
            float s2 = fmaxf(hi01, cv), mh = fminf(hi01, cv);
            float s0 = fminf(lo01, mh), s1 = fmaxf(lo01, mh);
            float h0 = xv * sc;
            float h1 = fmaf(xv, 2.f * sc, -s0 * sc);
            float h2 = fmaf(xv, 3.f * sc, (-s0 - s1) * sc);
            float h3 = fmaf(xv, 4.f * sc, (-s0 - s1 - s2) * sc);
            float m = fmaxf(fmaxf(h0, h1), fmaxf(h2, h3));
            float e0 = exp2f(h0 - m), e1 = exp2f(h1 - m);
            float e2 = exp2f(h2 - m), e3 = exp2f(h3 - m);
            float rs = 1.f / (e0 + e1 + e2 + e3);
            f32x4 b = {e0 * rs, e1 * rs, e2 * rs, e3 * rs};
            *(f32x4*)&BINS[rl * BINS_STRIDE + f * 4] = b;
        }
    }

    __syncthreads();

    // ---- per-thread geometry ----
    const int wave = tid >> 6, lane = tid & 63;
    const int rt = wave >> 2;            // row-tile (0..3)
    const int ks = wave & 3;             // K-split: l0 = ks
    const int r  = lane & 15;            // A-row within tile AND B/D column
    const int kg = lane >> 4;            // k-group
    const int rl = rt * 16 + r;          // local row

    const float* BR = &BINS[rl * BINS_STRIDE];
    f32x4 b0v = *(const f32x4*)&BR[0];
    f32x4 b1v = *(const f32x4*)&BR[4];
    f32x4 b2v = *(const f32x4*)&BR[8];
    f32x4 b3v = *(const f32x4*)&BR[12];
    f32x4 b4v = *(const f32x4*)&BR[16];
    f32x4 b5v = *(const f32x4*)&BR[20];

    // t8[j] = bins4[2*(kg&1)+(j>>2)] * bins5[j&3], as f32x2 pairs
    const int kgl = kg & 1, kgh = kg >> 1;
    f32x2 t8v[4];
    {
        float b4a = b4v[kgl * 2 + 0], b4b = b4v[kgl * 2 + 1];
        t8v[0] = (f32x2){b4a * b5v[0], b4a * b5v[1]};
        t8v[1] = (f32x2){b4a * b5v[2], b4a * b5v[3]};
        t8v[2] = (f32x2){b4b * b5v[0], b4b * b5v[1]};
        t8v[3] = (f32x2){b4b * b5v[2], b4b * b5v[3]};
    }
    const float b3e = b3v[kgh];          // even mstep: l3 = kg>>1
    const float b3o = b3v[2 + kgh];      // odd  mstep: l3 = 2 + (kg>>1)
    const float b0  = b0v[ks];

    // ---- B-read base addresses (swizzle bits 4-5 in base, bit 6 via even/odd) ----
    const int n_eff = (r < NCLASS) ? r : 9;
    const unsigned base0 = ((unsigned)n_eff << 13) +
                           ((((unsigned)kg) << 4) ^ ((((unsigned)n_eff) & 3u) << 4));
    const unsigned c6 = (((unsigned)n_eff) >> 2) & 1u;
    const int be = (int)(base0 + (c6 << 6)) + ks * 2048;
    const int bo = (int)(base0 + ((1u - c6) << 6)) + ks * 2048;

    // ---- K-loop: 32 MFMAs, A generated in-register ----
    f32x4 acc = {0.f, 0.f, 0.f, 0.f};
    #pragma unroll
    for (int m1 = 0; m1 < 4; ++m1) {
        const float b01 = b0 * b1v[m1];
        #pragma unroll
        for (int m2 = 0; m2 < 4; ++m2) {
            const float b012 = b01 * b2v[m2];
            const int off = (m1 * 4 + m2) * 128;
            {
                bf16x8 a = mk_a(t8v, b012 * b3e);
                bf16x8 b = *(const bf16x8*)(LS + (be + off));
                acc = __builtin_amdgcn_mfma_f32_16x16x32_bf16(a, b, acc, 0, 0, 0);
            }
            {
                bf16x8 a = mk_a(t8v, b012 * b3o);
                bf16x8 b = *(const bf16x8*)(LS + (bo + off));
                acc = __builtin_amdgcn_mfma_f32_16x16x32_bf16(a, b, acc, 0, 0, 0);
            }
        }
    }

    // ---- reduce K-split partials through LDS (reuse B region) ----
    __syncthreads();
    float* red = (float*)LS;
    *(f32x4*)&red[((size_t)wave * 64 + lane) * 4] = acc;
    __syncthreads();
    if (ks == 0) {
        f32x4 p1 = *(f32x4*)&red[(((size_t)rt * 4 + 1) * 64 + lane) * 4];
        f32x4 p2 = *(f32x4*)&red[(((size_t)rt * 4 + 2) * 64 + lane) * 4];
        f32x4 p3 = *(f32x4*)&red[(((size_t)rt * 4 + 3) * 64 + lane) * 4];
        f32x4 tot = acc + p1 + p2 + p3;
        if (r < NCLASS) {   // D: col = lane&15 = class, row = kg*4 + q
            #pragma unroll
            for (int q = 0; q < 4; ++q) {
                int grow = (blockIdx.x << 6) + (rt << 4) + kg * 4 + q;
                out[(size_t)grow * NCLASS + r] = tot[q];
            }
        }
    }
}

extern "C" void kernel_launch(void* const* d_in, const int* in_sizes, int n_in,
                              void* d_out, int out_size, void* d_ws, size_t ws_size,
                              hipStream_t stream) {
    const float* x           = (const float*)d_in[0];
    const float* cuts        = (const float*)d_in[1];
    const float* leaf_score  = (const float*)d_in[2];
    const float* temperature = (const float*)d_in[3];
    float* out = (float*)d_out;
    // 16384 rows / 64 rows-per-block = 256 blocks (1 per CU), 16 waves each
    dndt_mfma<<<256, 1024, 0, stream>>>(x, cuts, leaf_score, temperature, out);
}